// Round 1
// 80.557 us; speedup vs baseline: 1.1223x; 1.1223x over previous
//
#include <hip/hip_runtime.h>
#include <math.h>

#define NC    24
#define NPTS  1536
#define NH    40
#define FEPS  1e-8f
#define GROUPS 12
#define JPG    2    // hulls per group (NC / GROUPS)
#define TPB   256

// Bool-mask format detection: rows begin with >=768 (cmask) / >=16 (hmask)
// 'true' entries, so the first 32-bit word disambiguates:
// uint8 -> 0x01010101, int32 -> 1, f32 -> 1.0f
__device__ __forceinline__ int mask_fmt(const void* m) {
    int w = ((const int*)m)[0];
    if (w == 1) return 1;            // int32
    if (w == 0x3f800000) return 2;   // float32
    return 0;                        // uint8 / numpy bool
}
__device__ __forceinline__ bool mask_at(const void* m, int idx, int fmt) {
    if (fmt == 1) return ((const int*)m)[idx] != 0;
    if (fmt == 2) return ((const float*)m)[idx] != 0.0f;
    return ((const unsigned char*)m)[idx] != 0;
}

// Single fused kernel: grid (NPTS/TPB, NC, GROUPS).
// Staging phase: threads 0..JPG*NH-1 each transform one hull edge of this
// block's hull group into LDS (redundant across blocks, but ~30 ops vs the
// 560-op inner loop — removes the serial prep kernel + launch dependency
// + workspace entirely). Threads JPG*NH..+JPG compute hull_ok.
// Eval phase: each thread transforms its point once and sweeps JPG x NH
// edges from LDS (wave-uniform broadcast reads, conflict-free).
__global__ __launch_bounds__(TPB)
void fused_kernel(const float* __restrict__ pts, const float* __restrict__ hulls,
                  const float* __restrict__ med, const float* __restrict__ ang,
                  const float* __restrict__ trans,
                  const void* __restrict__ cmask, const void* __restrict__ hmask,
                  float* __restrict__ out)
{
    const int tid = threadIdx.x;
    const int i  = blockIdx.y;        // point cluster
    const int z  = blockIdx.z;        // hull group
    const int j0 = z * JPG;

    __shared__ float4 s_e[JPG * NH];   // {ex, ey, c0, w1}  w1 = 1/(len+eps) or 0
    __shared__ float  s_big[JPG * NH]; // 0 valid / +INF invalid (additive sentinel)
    __shared__ int    s_ok[JPG];
    __shared__ float  s_part[4];

    if (tid < JPG * NH) {
        const int g = tid / NH, h = tid - g * NH;
        const int j = j0 + g;
        float sj, cj;
        __sincosf(ang[j], &sj, &cj);
        const float mx = med[2*j], my = med[2*j+1];
        const float tx = trans[2*j], ty = trans[2*j+1];
        const int hn = (h + 1 == NH) ? 0 : h + 1;
        const float2 v1 = ((const float2*)hulls)[j*NH + h ];
        const float2 v2 = ((const float2*)hulls)[j*NH + hn];
        const float cx1 = v1.x - mx, cy1 = v1.y - my;
        const float p1x = cx1*cj - cy1*sj + mx + tx;
        const float p1y = cx1*sj + cy1*cj + my + ty;
        const float cx2 = v2.x - mx, cy2 = v2.y - my;
        const float p2x = cx2*cj - cy2*sj + mx + tx;
        const float p2y = cx2*sj + cy2*cj + my + ty;
        const float ex = p2x - p1x, ey = p2y - p1y;
        const float el = sqrtf(ex*ex + ey*ey);
        const bool valid = el > 1e-6f;
        const float inv = valid ? 1.0f / (el + FEPS) : 0.0f;
        const float c0 = ex*p1y - ey*p1x;
        s_e[tid]   = make_float4(ex, ey, c0, inv);
        s_big[tid] = valid ? 0.0f : INFINITY;
    } else if (tid < JPG * NH + JPG) {
        const int g = tid - JPG * NH;
        const int hfmt = mask_fmt(hmask);
        int cnt = 0;
        for (int h = 0; h < NH; ++h) cnt += mask_at(hmask, (j0+g)*NH + h, hfmt) ? 1 : 0;
        s_ok[g] = (cnt >= 3) ? 1 : 0;
    }
    __syncthreads();

    // transform this thread's point with cluster-i params
    const int n = blockIdx.x * TPB + tid;
    const int cfmt = mask_fmt(cmask);
    const bool pm = mask_at(cmask, i*NPTS + n, cfmt);
    float si, ci;
    __sincosf(ang[i], &si, &ci);
    const float mx = med[2*i], my = med[2*i+1];
    const float tx = trans[2*i], ty = trans[2*i+1];
    const float2 p = ((const float2*)pts)[i*NPTS + n];
    const float cx = p.x - mx, cy = p.y - my;
    const float px = cx*ci - cy*si + mx + tx;
    const float py = cx*si + cy*ci + my + ty;

    float acc = 0.f;
    for (int g = 0; g < JPG; ++g) {
        const int j = j0 + g;
        if (j == i || !s_ok[g]) continue;      // uniform across block
        // all_pos  <=> min over edges of sgn >= -EPS  (invalid edges give sgn=0: passes)
        // all_neg  <=> max over edges of sgn <= +EPS
        // min_abs: |sgn| + big  (big=+INF for invalid; sgn is exactly 0 there, no NaN)
        float mn = INFINITY, mxs = -INFINITY, ma = INFINITY;
#pragma unroll
        for (int h = 0; h < NH; ++h) {
            const float4 e  = s_e[g*NH + h];
            const float big = s_big[g*NH + h];
            const float t  = fmaf(e.y, px, e.z);       // ey*px + c0
            const float cr = fmaf(e.x, py, -t);        // ex*py - (ey*px + c0)
            const float sg = cr * e.w;
            mn  = fminf(mn,  sg);
            mxs = fmaxf(mxs, sg);
            ma  = fminf(ma, fabsf(sg) + big);
        }
        if (mn >= -FEPS || mxs <= FEPS)
            acc += 1.0f / (1.0f + __expf(-ma));        // sigmoid; inf -> 1 matches ref
    }
    if (!pm) acc = 0.f;

    // translation/rotation penalty: one thread of one (light) block.
    // Block (0, i=0, z=0) skips its g==0 hull (j==i), so it's under-loaded.
    if (blockIdx.x == 0 && i == 0 && z == 0 && tid == TPB - 1) {
        float pen = 0.f;
        for (int c = 0; c < NC; ++c) {
            const float tcx = trans[2*c], tcy = trans[2*c+1], a = ang[c];
            pen += 0.1f * (tcx*tcx + tcy*tcy) + 1.0f * (a*a);
        }
        acc += pen;   // after the pm-zeroing: penalty must not be masked
    }

    // block reduction: wave shuffle then LDS across the 4 waves
#pragma unroll
    for (int off = 32; off > 0; off >>= 1)
        acc += __shfl_down(acc, off, 64);
    const int lane = tid & 63, wid = tid >> 6;
    if (lane == 0) s_part[wid] = acc;
    __syncthreads();
    if (tid == 0) {
        const float v = s_part[0] + s_part[1] + s_part[2] + s_part[3];
        if (v != 0.f) atomicAdd(out, v);   // skip zero-contribution blocks
    }
}

extern "C" void kernel_launch(void* const* d_in, const int* in_sizes, int n_in,
                              void* d_out, int out_size, void* d_ws, size_t ws_size,
                              hipStream_t stream) {
    const float* pts   = (const float*)d_in[0];   // (C,N,2)
    const float* hulls = (const float*)d_in[1];   // (C,H,2)
    const float* med   = (const float*)d_in[2];   // (C,2)
    const float* ang   = (const float*)d_in[3];   // (C,)
    const float* trans = (const float*)d_in[4];   // (C,2)
    const void*  cmask = d_in[5];                 // (C,N) bool
    const void*  hmask = d_in[6];                 // (C,H) bool
    float* out = (float*)d_out;

    (void)d_ws; (void)ws_size;                    // workspace no longer used

    hipMemsetAsync(out, 0, sizeof(float), stream);
    dim3 grid(NPTS / TPB, NC, GROUPS);            // 6 x 24 x 12 = 1728 blocks = 6.75/CU
    fused_kernel<<<grid, dim3(TPB, 1, 1), 0, stream>>>(pts, hulls, med, ang, trans,
                                                       cmask, hmask, out);
}